// Round 1
// 642.581 us; speedup vs baseline: 1.0140x; 1.0140x over previous
//
#include <hip/hip_runtime.h>

#define N_NODES 50000
#define F0 256
#define F1 128
#define F2 64
#define BN_EPS 1e-5f

typedef float f32x4 __attribute__((ext_vector_type(4)));
typedef __bf16 bf16x8 __attribute__((ext_vector_type(8)));
typedef unsigned short ushort8v __attribute__((ext_vector_type(8)));

__device__ __forceinline__ float bflo(unsigned v) { return __uint_as_float(v << 16); }
__device__ __forceinline__ float bfhi(unsigned v) { return __uint_as_float(v & 0xFFFF0000u); }
__device__ __forceinline__ unsigned short f2bf(float f) {
  unsigned u = __float_as_uint(f);
  u += 0x7FFFu + ((u >> 16) & 1u);
  return (unsigned short)(u >> 16);
}
__device__ __forceinline__ void split2(float a, unsigned short& hi, unsigned short& lo) {
  hi = f2bf(a);
  float hf = __uint_as_float((unsigned)hi << 16);
  lo = f2bf(a - hf);
}
__device__ __forceinline__ int rdl(int v, int l) { return __builtin_amdgcn_readlane(v, l); }
__device__ __forceinline__ float rdlf(float v, int l) {
  return __uint_as_float((unsigned)__builtin_amdgcn_readlane(__float_as_int(v), l));
}

// ---------------- CSR build ----------------
__global__ void count_dst(const int* __restrict__ dst, int* __restrict__ counts, int E) {
  int e = blockIdx.x * blockDim.x + threadIdx.x;
  if (e < E) atomicAdd(&counts[dst[e]], 1);
}

// hierarchical scan pass 1: 49 blocks x 256 threads x 4 elems; also emits dinv
__global__ __launch_bounds__(256) void scan_blocks(const int* __restrict__ counts,
                                                   int* __restrict__ offs,
                                                   int* __restrict__ bsum,
                                                   float* __restrict__ dinv) {
  __shared__ int s_w[4];
  const int tid = threadIdx.x, lane = tid & 63, wid = tid >> 6;
  const int base = blockIdx.x * 1024 + tid * 4;
  int v0 = 0, v1 = 0, v2 = 0, v3 = 0;
  if (base + 3 < N_NODES) {
    int4 v = *(const int4*)(counts + base);
    v0 = v.x; v1 = v.y; v2 = v.z; v3 = v.w;
  } else if (base < N_NODES) {
    v0 = counts[base];
    if (base + 1 < N_NODES) v1 = counts[base + 1];
    if (base + 2 < N_NODES) v2 = counts[base + 2];
  }
  if (base < N_NODES) {
    dinv[base] = rsqrtf((float)v0 + 1.0f);
    if (base + 1 < N_NODES) dinv[base + 1] = rsqrtf((float)v1 + 1.0f);
    if (base + 2 < N_NODES) dinv[base + 2] = rsqrtf((float)v2 + 1.0f);
    if (base + 3 < N_NODES) dinv[base + 3] = rsqrtf((float)v3 + 1.0f);
  }
  int t = v0 + v1 + v2 + v3;
  int incl = t;
#pragma unroll
  for (int d = 1; d < 64; d <<= 1) {
    int x = __shfl_up(incl, d);
    if (lane >= d) incl += x;
  }
  if (lane == 63) s_w[wid] = incl;
  __syncthreads();
  int woff = 0;
#pragma unroll
  for (int j = 0; j < 4; j++)
    if (j < wid) woff += s_w[j];
  int p = woff + incl - t;
  if (base < N_NODES) offs[base] = p;
  p += v0;
  if (base + 1 < N_NODES) offs[base + 1] = p;
  p += v1;
  if (base + 2 < N_NODES) offs[base + 2] = p;
  p += v2;
  if (base + 3 < N_NODES) offs[base + 3] = p;
  if (tid == 255) bsum[blockIdx.x] = woff + incl;  // block total
}

// pass 2: single wave scans <=64 block sums -> exclusive; writes grand total
__global__ void scan_tops(int* __restrict__ bsum, int* __restrict__ offs, int nblk) {
  int lane = threadIdx.x;
  int v = (lane < nblk) ? bsum[lane] : 0;
  int incl = v;
#pragma unroll
  for (int d = 1; d < 64; d <<= 1) {
    int x = __shfl_up(incl, d);
    if (lane >= d) incl += x;
  }
  if (lane < nblk) bsum[lane] = incl - v;
  if (lane == 63) offs[N_NODES] = incl;
}

// pass 3: add block offsets back
__global__ __launch_bounds__(256) void scan_add(int* __restrict__ offs,
                                                const int* __restrict__ bsum) {
  const int add = bsum[blockIdx.x];
  const int base = blockIdx.x * 1024 + threadIdx.x * 4;
  if (base + 3 < N_NODES) {
    int4 v = *(const int4*)(offs + base);
    v.x += add; v.y += add; v.z += add; v.w += add;
    *(int4*)(offs + base) = v;
  } else if (base < N_NODES) {
    offs[base] += add;
    if (base + 1 < N_NODES) offs[base + 1] += add;
    if (base + 2 < N_NODES) offs[base + 2] += add;
  }
}

__global__ void fill_csr(const int* __restrict__ src, const int* __restrict__ dst,
                         const int* __restrict__ offs, int* __restrict__ cursor,
                         const float* __restrict__ dinv,
                         int* __restrict__ csr_src, float* __restrict__ csr_w, int E) {
  int e = blockIdx.x * blockDim.x + threadIdx.x;
  if (e < E) {
    int s = src[e], d = dst[e];
    int p = offs[d] + atomicAdd(&cursor[d], 1);
    csr_src[p] = s;
    csr_w[p] = dinv[s] * dinv[d];
  }
}

__global__ void compute_rowsum(const int* __restrict__ offs, const float* __restrict__ csr_w,
                               const float* __restrict__ dinv, float* __restrict__ rowsum) {
  int i = blockIdx.x * blockDim.x + threadIdx.x;
  if (i < N_NODES) {
    float s = dinv[i] * dinv[i];
    int e1 = offs[i + 1];
    for (int e = offs[i]; e < e1; e++) s += csr_w[e];
    rowsum[i] = s;
  }
}

// ---------------- merged weight conversion: W[K][N] fp32 -> hi/lo [N][K] bf16 ----------------
__device__ __forceinline__ void wt_one(const float* W, unsigned short* Wh, unsigned short* Wl,
                                       int K, int N, int idx) {
  int k = idx / N, n = idx - k * N;
  unsigned short h, l;
  split2(W[idx], h, l);
  Wh[(size_t)n * K + k] = h;
  Wl[(size_t)n * K + k] = l;
}

__global__ void convert_weights(const float* __restrict__ We1, const float* __restrict__ We2,
                                const float* __restrict__ Wd1, const float* __restrict__ Wd2,
                                unsigned short* W1h, unsigned short* W1l,
                                unsigned short* W2h, unsigned short* W2l,
                                unsigned short* W3h, unsigned short* W3l,
                                unsigned short* W4h, unsigned short* W4l) {
  int idx = blockIdx.x * blockDim.x + threadIdx.x;
  if (idx < 32768) {
    wt_one(We1, W1h, W1l, 256, 128, idx);
  } else if (idx < 40960) {
    wt_one(We2, W2h, W2l, 128, 64, idx - 32768);
  } else if (idx < 49152) {
    wt_one(Wd1, W3h, W3l, 64, 128, idx - 40960);
  } else if (idx < 81920) {
    wt_one(Wd2, W4h, W4l, 128, 256, idx - 49152);
  }
}

// ---------------- split-bf16 MFMA GEMM ----------------
template <int BN, bool STATS, bool AF32>
__global__ __launch_bounds__(256) void mfma_gemm_split(
    const unsigned short* __restrict__ Ahi, const unsigned short* __restrict__ Alo,
    const float* __restrict__ Af,
    const unsigned short* __restrict__ Whi, const unsigned short* __restrict__ Wlo,
    const float* __restrict__ bias, const float* __restrict__ rowsum,
    unsigned short* __restrict__ Cb, float* __restrict__ Cf,
    float* __restrict__ stat, int M, int K, int N) {
  constexpr int BM = 128;
  constexpr int MT = (BN == 128) ? 4 : 2;
  constexpr int NT = 4;
  __shared__ __align__(16) unsigned short AsH[4][BM][8];
  __shared__ __align__(16) unsigned short AsL[4][BM][8];
  __shared__ __align__(16) unsigned short BsH[4][BN][8];
  __shared__ __align__(16) unsigned short BsL[4][BN][8];
  const int tid = threadIdx.x;
  const int lane = tid & 63, wid = tid >> 6;
  const int quad = lane >> 4, ln = lane & 15;
  const int m0 = blockIdx.x * BM;
  const int n0 = blockIdx.y * BN;
  const int wm = (BN == 128) ? (wid & 1) * 64 : wid * 32;
  const int wn = (BN == 128) ? (wid >> 1) * 64 : 0;
  f32x4 acc[MT][NT] = {};

  const int arow = tid >> 2, aseg = tid & 3;
  for (int k0 = 0; k0 < K; k0 += 32) {
#pragma unroll
    for (int i = 0; i < 2; i++) {
      int row = arow + i * 64;
      int gm = m0 + row;
      if (AF32) {
        float4 u0 = make_float4(0.f, 0.f, 0.f, 0.f), u1 = u0;
        if (gm < M) {
          u0 = *(const float4*)(Af + (size_t)gm * K + k0 + aseg * 8);
          u1 = *(const float4*)(Af + (size_t)gm * K + k0 + aseg * 8 + 4);
        }
        ushort4 h0, l0, h1, l1;
        split2(u0.x, h0.x, l0.x); split2(u0.y, h0.y, l0.y);
        split2(u0.z, h0.z, l0.z); split2(u0.w, h0.w, l0.w);
        split2(u1.x, h1.x, l1.x); split2(u1.y, h1.y, l1.y);
        split2(u1.z, h1.z, l1.z); split2(u1.w, h1.w, l1.w);
        *(ushort4*)(&AsH[aseg][row][0]) = h0;
        *(ushort4*)(&AsH[aseg][row][4]) = h1;
        *(ushort4*)(&AsL[aseg][row][0]) = l0;
        *(ushort4*)(&AsL[aseg][row][4]) = l1;
      } else {
        ushort8v vh = {0, 0, 0, 0, 0, 0, 0, 0};
        ushort8v vl = {0, 0, 0, 0, 0, 0, 0, 0};
        if (gm < M) {
          vh = *(const ushort8v*)(Ahi + (size_t)gm * K + k0 + aseg * 8);
          vl = *(const ushort8v*)(Alo + (size_t)gm * K + k0 + aseg * 8);
        }
        *(ushort8v*)(&AsH[aseg][row][0]) = vh;
        *(ushort8v*)(&AsL[aseg][row][0]) = vl;
      }
    }
#pragma unroll
    for (int i = 0; i < BN / 64; i++) {
      int n = arow + i * 64;
      *(ushort8v*)(&BsH[aseg][n][0]) =
          *(const ushort8v*)(Whi + (size_t)(n0 + n) * K + k0 + aseg * 8);
      *(ushort8v*)(&BsL[aseg][n][0]) =
          *(const ushort8v*)(Wlo + (size_t)(n0 + n) * K + k0 + aseg * 8);
    }
    __syncthreads();
    bf16x8 ah[MT], al[MT], bh[NT], bl[NT];
#pragma unroll
    for (int mt = 0; mt < MT; mt++) {
      ah[mt] = *(const bf16x8*)(&AsH[quad][wm + mt * 16 + ln][0]);
      al[mt] = *(const bf16x8*)(&AsL[quad][wm + mt * 16 + ln][0]);
    }
#pragma unroll
    for (int nt = 0; nt < NT; nt++) {
      bh[nt] = *(const bf16x8*)(&BsH[quad][wn + nt * 16 + ln][0]);
      bl[nt] = *(const bf16x8*)(&BsL[quad][wn + nt * 16 + ln][0]);
    }
#pragma unroll
    for (int mt = 0; mt < MT; mt++)
#pragma unroll
      for (int nt = 0; nt < NT; nt++) {
        acc[mt][nt] = __builtin_amdgcn_mfma_f32_16x16x32_bf16(ah[mt], bl[nt], acc[mt][nt], 0, 0, 0);
        acc[mt][nt] = __builtin_amdgcn_mfma_f32_16x16x32_bf16(al[mt], bh[nt], acc[mt][nt], 0, 0, 0);
        acc[mt][nt] = __builtin_amdgcn_mfma_f32_16x16x32_bf16(ah[mt], bh[nt], acc[mt][nt], 0, 0, 0);
      }
    __syncthreads();
  }

  if (!STATS) {
#pragma unroll
    for (int nt = 0; nt < NT; nt++) {
      int gn = n0 + wn + nt * 16 + ln;
      float bv = bias[gn];
#pragma unroll
      for (int mt = 0; mt < MT; mt++) {
#pragma unroll
        for (int r = 0; r < 4; r++) {
          int gm = m0 + wm + mt * 16 + quad * 4 + r;
          if (gm < M) Cb[(size_t)gm * N + gn] = f2bf(acc[mt][nt][r] + bv);
        }
      }
    }
  } else {
    float rs[MT][4];
#pragma unroll
    for (int mt = 0; mt < MT; mt++)
#pragma unroll
      for (int r = 0; r < 4; r++) {
        int gm = m0 + wm + mt * 16 + quad * 4 + r;
        rs[mt][r] = (gm < M) ? rowsum[gm] : 0.f;
      }
#pragma unroll
    for (int nt = 0; nt < NT; nt++) {
      int gn = n0 + wn + nt * 16 + ln;
      float bv = bias[gn];
      float ls = 0.f, lq = 0.f;
#pragma unroll
      for (int mt = 0; mt < MT; mt++) {
#pragma unroll
        for (int r = 0; r < 4; r++) {
          int gm = m0 + wm + mt * 16 + quad * 4 + r;
          if (gm < M) {
            float v = fmaxf(fmaf(bv, rs[mt][r], acc[mt][nt][r]), 0.f);
            Cf[(size_t)gm * N + gn] = v;
            ls += v;
            lq = fmaf(v, v, lq);
          }
        }
      }
      ls += __shfl_xor(ls, 16); ls += __shfl_xor(ls, 32);
      lq += __shfl_xor(lq, 16); lq += __shfl_xor(lq, 32);
      if (quad == 0) {
        atomicAdd(&stat[gn], ls);
        atomicAdd(&stat[256 + gn], lq);
      }
    }
  }
}

// ---------------- agg F=128: half-wave per edge, dwordx2 gathers (2 edges/load) ----------------
template <bool RELU_STATS, bool OUT_SPLIT>
__global__ __launch_bounds__(256) void agg128_rl(
    const unsigned short* __restrict__ hb, const int* __restrict__ offs,
    const int* __restrict__ csr_src, const float* __restrict__ csr_w,
    const float* __restrict__ dinv, float* __restrict__ outf,
    unsigned short* __restrict__ outhi, unsigned short* __restrict__ outlo,
    float* __restrict__ stat) {
  const int tid = threadIdx.x;
  const int lane = tid & 63;
  const int widx = tid >> 6;
  const int half = lane >> 5;   // which edge of the pair this lane serves
  const int hl = lane & 31;     // 32 lanes x 8B = 256B row; 4 features/lane
  const int nwaves = gridDim.x * 4;
  float ls0 = 0.f, ls1 = 0.f, ls2 = 0.f, ls3 = 0.f;
  float lq0 = 0.f, lq1 = 0.f, lq2 = 0.f, lq3 = 0.f;

  for (int node = blockIdx.x * 4 + widx; node < N_NODES; node += nwaves) {
    const int e0 = __builtin_amdgcn_readfirstlane(offs[node]);
    const int e1 = __builtin_amdgcn_readfirstlane(offs[node + 1]);
    float a0 = 0.f, a1 = 0.f, a2 = 0.f, a3 = 0.f;
    for (int e = e0; e < e1; e += 64) {
      const int cnt = min(64, e1 - e);
      int idx = 0;
      float wt = 0.f;
      if (lane < cnt) {
        idx = csr_src[e + lane];
        wt = csr_w[e + lane];
      }
      const int nb = (cnt + 15) & ~15;
      for (int j = 0; j < nb; j += 16) {
#pragma unroll
        for (int u = 0; u < 8; u++) {
          int sa = rdl(idx, j + 2 * u);
          int sb = rdl(idx, j + 2 * u + 1);
          float wa = rdlf(wt, j + 2 * u);
          float wb = rdlf(wt, j + 2 * u + 1);
          int s = half ? sb : sa;
          float w = half ? wb : wa;
          uint2 v = *(const uint2*)(hb + (size_t)s * 128 + hl * 4);
          a0 = fmaf(bflo(v.x), w, a0);
          a1 = fmaf(bfhi(v.x), w, a1);
          a2 = fmaf(bflo(v.y), w, a2);
          a3 = fmaf(bfhi(v.y), w, a3);
        }
      }
    }
    a0 += __shfl_xor(a0, 32);
    a1 += __shfl_xor(a1, 32);
    a2 += __shfl_xor(a2, 32);
    a3 += __shfl_xor(a3, 32);
    float di = dinv[node];
    float ds = di * di;
    uint2 vs = *(const uint2*)(hb + (size_t)node * 128 + hl * 4);
    a0 = fmaf(bflo(vs.x), ds, a0);
    a1 = fmaf(bfhi(vs.x), ds, a1);
    a2 = fmaf(bflo(vs.y), ds, a2);
    a3 = fmaf(bfhi(vs.y), ds, a3);
    if (RELU_STATS) {
      a0 = fmaxf(a0, 0.f);
      a1 = fmaxf(a1, 0.f);
      a2 = fmaxf(a2, 0.f);
      a3 = fmaxf(a3, 0.f);
      if (half == 0) {
        ls0 += a0; ls1 += a1; ls2 += a2; ls3 += a3;
        lq0 = fmaf(a0, a0, lq0);
        lq1 = fmaf(a1, a1, lq1);
        lq2 = fmaf(a2, a2, lq2);
        lq3 = fmaf(a3, a3, lq3);
      }
    }
    if (half == 0) {
      if (OUT_SPLIT) {
        unsigned short h0, l0, h1, l1, h2, l2, h3, l3;
        split2(a0, h0, l0);
        split2(a1, h1, l1);
        split2(a2, h2, l2);
        split2(a3, h3, l3);
        ushort4 hv, lv;
        hv.x = h0; hv.y = h1; hv.z = h2; hv.w = h3;
        lv.x = l0; lv.y = l1; lv.z = l2; lv.w = l3;
        *(ushort4*)(outhi + (size_t)node * 128 + hl * 4) = hv;
        *(ushort4*)(outlo + (size_t)node * 128 + hl * 4) = lv;
      } else {
        *(float4*)(outf + (size_t)node * 128 + hl * 4) = make_float4(a0, a1, a2, a3);
      }
    }
  }

  if (RELU_STATS) {
    __shared__ float red[4][128];
    if (half == 0) {
      red[widx][hl * 4 + 0] = ls0;
      red[widx][hl * 4 + 1] = ls1;
      red[widx][hl * 4 + 2] = ls2;
      red[widx][hl * 4 + 3] = ls3;
    }
    __syncthreads();
    if (tid < 128) {
      atomicAdd(&stat[tid], red[0][tid] + red[1][tid] + red[2][tid] + red[3][tid]);
    }
    __syncthreads();
    if (half == 0) {
      red[widx][hl * 4 + 0] = lq0;
      red[widx][hl * 4 + 1] = lq1;
      red[widx][hl * 4 + 2] = lq2;
      red[widx][hl * 4 + 3] = lq3;
    }
    __syncthreads();
    if (tid < 128) {
      atomicAdd(&stat[256 + tid], red[0][tid] + red[1][tid] + red[2][tid] + red[3][tid]);
    }
  }
}

// ---------------- agg F=64: quarter-wave per edge, dwordx2 gathers (4 edges/load) ----------------
template <bool RELU_STATS, bool OUT_SPLIT>
__global__ __launch_bounds__(256) void agg64_rl(
    const unsigned short* __restrict__ hb, const int* __restrict__ offs,
    const int* __restrict__ csr_src, const float* __restrict__ csr_w,
    const float* __restrict__ dinv, float* __restrict__ outf,
    unsigned short* __restrict__ outhi, unsigned short* __restrict__ outlo,
    float* __restrict__ stat) {
  const int tid = threadIdx.x;
  const int lane = tid & 63;
  const int widx = tid >> 6;
  const int ql = lane & 15;  // 16 lanes x 8B = 128B row; 4 features/lane
  const int nwaves = gridDim.x * 4;
  float ls0 = 0.f, ls1 = 0.f, ls2 = 0.f, ls3 = 0.f;
  float lq0 = 0.f, lq1 = 0.f, lq2 = 0.f, lq3 = 0.f;

  for (int node = blockIdx.x * 4 + widx; node < N_NODES; node += nwaves) {
    const int e0 = __builtin_amdgcn_readfirstlane(offs[node]);
    const int e1 = __builtin_amdgcn_readfirstlane(offs[node + 1]);
    float a0 = 0.f, a1 = 0.f, a2 = 0.f, a3 = 0.f;
    for (int e = e0; e < e1; e += 64) {
      const int cnt = min(64, e1 - e);
      int idx = 0;
      float wt = 0.f;
      if (lane < cnt) {
        idx = csr_src[e + lane];
        wt = csr_w[e + lane];
      }
      const int nb = (cnt + 31) & ~31;
      for (int j = 0; j < nb; j += 32) {
#pragma unroll
        for (int u = 0; u < 8; u++) {
          int s0 = rdl(idx, j + 4 * u + 0);
          int s1 = rdl(idx, j + 4 * u + 1);
          int s2 = rdl(idx, j + 4 * u + 2);
          int s3 = rdl(idx, j + 4 * u + 3);
          float w0 = rdlf(wt, j + 4 * u + 0);
          float w1 = rdlf(wt, j + 4 * u + 1);
          float w2 = rdlf(wt, j + 4 * u + 2);
          float w3 = rdlf(wt, j + 4 * u + 3);
          int sx = (lane & 16) ? s1 : s0;
          int sy = (lane & 16) ? s3 : s2;
          int s = (lane & 32) ? sy : sx;
          float wx = (lane & 16) ? w1 : w0;
          float wy = (lane & 16) ? w3 : w2;
          float w = (lane & 32) ? wy : wx;
          uint2 v = *(const uint2*)(hb + (size_t)s * 64 + ql * 4);
          a0 = fmaf(bflo(v.x), w, a0);
          a1 = fmaf(bfhi(v.x), w, a1);
          a2 = fmaf(bflo(v.y), w, a2);
          a3 = fmaf(bfhi(v.y), w, a3);
        }
      }
    }
    a0 += __shfl_xor(a0, 16); a0 += __shfl_xor(a0, 32);
    a1 += __shfl_xor(a1, 16); a1 += __shfl_xor(a1, 32);
    a2 += __shfl_xor(a2, 16); a2 += __shfl_xor(a2, 32);
    a3 += __shfl_xor(a3, 16); a3 += __shfl_xor(a3, 32);
    float di = dinv[node];
    float ds = di * di;
    uint2 vs = *(const uint2*)(hb + (size_t)node * 64 + ql * 4);
    a0 = fmaf(bflo(vs.x), ds, a0);
    a1 = fmaf(bfhi(vs.x), ds, a1);
    a2 = fmaf(bflo(vs.y), ds, a2);
    a3 = fmaf(bfhi(vs.y), ds, a3);
    if (RELU_STATS) {
      a0 = fmaxf(a0, 0.f);
      a1 = fmaxf(a1, 0.f);
      a2 = fmaxf(a2, 0.f);
      a3 = fmaxf(a3, 0.f);
      if (lane < 16) {
        ls0 += a0; ls1 += a1; ls2 += a2; ls3 += a3;
        lq0 = fmaf(a0, a0, lq0);
        lq1 = fmaf(a1, a1, lq1);
        lq2 = fmaf(a2, a2, lq2);
        lq3 = fmaf(a3, a3, lq3);
      }
    }
    if (lane < 16) {
      if (OUT_SPLIT) {
        unsigned short h0, l0, h1, l1, h2, l2, h3, l3;
        split2(a0, h0, l0);
        split2(a1, h1, l1);
        split2(a2, h2, l2);
        split2(a3, h3, l3);
        ushort4 hv, lv;
        hv.x = h0; hv.y = h1; hv.z = h2; hv.w = h3;
        lv.x = l0; lv.y = l1; lv.z = l2; lv.w = l3;
        *(ushort4*)(outhi + (size_t)node * 64 + ql * 4) = hv;
        *(ushort4*)(outlo + (size_t)node * 64 + ql * 4) = lv;
      } else {
        *(float4*)(outf + (size_t)node * 64 + ql * 4) = make_float4(a0, a1, a2, a3);
      }
    }
  }

  if (RELU_STATS) {
    __shared__ float red[4][64];
    if (lane < 16) {
      red[widx][ql * 4 + 0] = ls0;
      red[widx][ql * 4 + 1] = ls1;
      red[widx][ql * 4 + 2] = ls2;
      red[widx][ql * 4 + 3] = ls3;
    }
    __syncthreads();
    if (tid < 64) {
      atomicAdd(&stat[tid], red[0][tid] + red[1][tid] + red[2][tid] + red[3][tid]);
    }
    __syncthreads();
    if (lane < 16) {
      red[widx][ql * 4 + 0] = lq0;
      red[widx][ql * 4 + 1] = lq1;
      red[widx][ql * 4 + 2] = lq2;
      red[widx][ql * 4 + 3] = lq3;
    }
    __syncthreads();
    if (tid < 64) {
      atomicAdd(&stat[256 + tid], red[0][tid] + red[1][tid] + red[2][tid] + red[3][tid]);
    }
  }
}

// ---------------- BN apply with inline finalize ----------------
template <int F, bool RELU, bool WF32, bool WB16, bool WSPLIT>
__global__ __launch_bounds__(256) void bn_apply_f(const float* __restrict__ a,
                                                  const float* __restrict__ stat,
                                                  const float* __restrict__ g,
                                                  const float* __restrict__ bb,
                                                  float* __restrict__ outf,
                                                  unsigned short* __restrict__ outb,
                                                  unsigned short* __restrict__ outhi,
                                                  unsigned short* __restrict__ outlo) {
  __shared__ float s_scale[F], s_shift[F];
  const int tid = threadIdx.x;
  if (tid < F) {
    const float invN = 1.0f / (float)N_NODES;
    float mean = stat[tid] * invN;
    float var = fmaxf(stat[256 + tid] * invN - mean * mean, 0.f);
    float inv = rsqrtf(var + BN_EPS);
    float sc = g[tid] * inv;
    s_scale[tid] = sc;
    s_shift[tid] = bb[tid] - mean * sc;
  }
  __syncthreads();
  constexpr int C4 = F / 4;
  const int total = N_NODES * C4;
  for (int idx = blockIdx.x * blockDim.x + tid; idx < total; idx += gridDim.x * blockDim.x) {
    int c4 = idx % C4;
    float4 v = ((const float4*)a)[idx];
    float4 s = *(float4*)&s_scale[c4 * 4];
    float4 sh = *(float4*)&s_shift[c4 * 4];
    float4 o;
    o.x = fmaf(v.x, s.x, sh.x);
    o.y = fmaf(v.y, s.y, sh.y);
    o.z = fmaf(v.z, s.z, sh.z);
    o.w = fmaf(v.w, s.w, sh.w);
    if (RELU) {
      o.x = fmaxf(o.x, 0.f);
      o.y = fmaxf(o.y, 0.f);
      o.z = fmaxf(o.z, 0.f);
      o.w = fmaxf(o.w, 0.f);
    }
    if (WF32) ((float4*)outf)[idx] = o;
    if (WB16) {
      ushort4 b;
      b.x = f2bf(o.x); b.y = f2bf(o.y); b.z = f2bf(o.z); b.w = f2bf(o.w);
      ((ushort4*)outb)[idx] = b;
    }
    if (WSPLIT) {
      ushort4 h, l;
      split2(o.x, h.x, l.x);
      split2(o.y, h.y, l.y);
      split2(o.z, h.z, l.z);
      split2(o.w, h.w, l.w);
      ((ushort4*)outhi)[idx] = h;
      ((ushort4*)outlo)[idx] = l;
    }
  }
}

extern "C" void kernel_launch(void* const* d_in, const int* in_sizes, int n_in,
                              void* d_out, int out_size, void* d_ws, size_t ws_size,
                              hipStream_t stream) {
  const float* x = (const float*)d_in[0];
  const int* ei = (const int*)d_in[1];
  const int E = in_sizes[1] / 2;
  const int* src = ei;
  const int* dst = ei + E;
  const float* We1 = (const float*)d_in[2];  const float* be1 = (const float*)d_in[3];
  const float* g1  = (const float*)d_in[4];  const float* bb1 = (const float*)d_in[5];
  const float* We2 = (const float*)d_in[6];  const float* be2 = (const float*)d_in[7];
  const float* g2  = (const float*)d_in[8];  const float* bb2 = (const float*)d_in[9];
  const float* Wd1 = (const float*)d_in[10]; const float* bd1 = (const float*)d_in[11];
  const float* g3  = (const float*)d_in[12]; const float* bb3 = (const float*)d_in[13];
  const float* Wd2 = (const float*)d_in[14]; const float* bd2 = (const float*)d_in[15];
  const float* g4  = (const float*)d_in[16]; const float* bb4 = (const float*)d_in[17];

  float* out = (float*)d_out;
  char* ws = (char*)d_ws;
  // Region A [0, 48MB): disjoint lifetimes per step:
  unsigned short* A0b  = (unsigned short*)(ws + 0);         // L1 gemm out 128ch bf16
  unsigned short* A1b  = (unsigned short*)(ws + 12800000);  // L2 gemm out 64ch bf16
  unsigned short* C2b  = (unsigned short*)(ws + 32000000);  // enc2 bf16 (L3 agg input)
  unsigned short* G3hi = (unsigned short*)(ws + 0);         // L3 agg out hi (6.4M)
  unsigned short* G3lo = (unsigned short*)(ws + 6400000);   // L3 agg out lo (6.4M)
  unsigned short* D3b  = (unsigned short*)(ws + 12800000);  // h3 bf16 (L4 agg input, 12.8M)
  unsigned short* G4hi = (unsigned short*)(ws + 0);         // L4 agg out hi (12.8M)
  unsigned short* G4lo = (unsigned short*)(ws + 25600000);  // L4 agg out lo (12.8M)
  unsigned short* Wb   = (unsigned short*)(ws + 48000000);  // weights, persist
  unsigned short* W1h = Wb;            unsigned short* W1l = W1h + 32768;
  unsigned short* W2h = W1l + 32768;   unsigned short* W2l = W2h + 8192;
  unsigned short* W3h = W2l + 8192;    unsigned short* W3l = W3h + 8192;
  unsigned short* W4h = W3l + 8192;    unsigned short* W4l = W4h + 32768;
  float* B0f  = (float*)(ws + 51200000);  // pre-BN fp32 (up to 51.2M at L4)
  int*   csrS   = (int*)(ws + 102400000);
  float* csrW   = (float*)(ws + 105600000);
  float* stat4  = (float*)(ws + 108800000);  // 4 x 512 floats
  int*   bsum   = (int*)(ws + 108808192);    // 64 ints for hierarchical scan
  int*   counts = (int*)(ws + 108810000);
  int*   cursor = (int*)(ws + 109010000);
  int*   offs   = (int*)(ws + 109210000);
  float* dinv   = (float*)(ws + 109410064);
  if (ws_size < 109604160) return;
  float* rowsum = (float*)cursor;  // reuse cursor region after fill_csr

  float* enc1 = out + (size_t)N_NODES * F0;
  float* enc2 = enc1 + (size_t)N_NODES * F1;

  const int EB = (E + 255) / 256;
  const int AGG_GRID = 2048;
  const int MB = (N_NODES + 127) / 128;  // 391
  const int SCAN_B = (N_NODES + 1023) / 1024;  // 49

  // conversions + CSR build
  convert_weights<<<320, 256, 0, stream>>>(We1, We2, Wd1, Wd2, W1h, W1l, W2h, W2l,
                                           W3h, W3l, W4h, W4l);
  hipMemsetAsync(counts, 0, 2 * N_NODES * sizeof(int) + 20000, stream);  // counts+cursor
  hipMemsetAsync(stat4, 0, 4 * 512 * sizeof(float), stream);
  count_dst<<<EB, 256, 0, stream>>>(dst, counts, E);
  scan_blocks<<<SCAN_B, 256, 0, stream>>>(counts, offs, bsum, dinv);
  scan_tops<<<1, 64, 0, stream>>>(bsum, offs, SCAN_B);
  scan_add<<<SCAN_B, 256, 0, stream>>>(offs, bsum);
  fill_csr<<<EB, 256, 0, stream>>>(src, dst, offs, cursor, dinv, csrS, csrW, E);
  compute_rowsum<<<(N_NODES + 255) / 256, 256, 0, stream>>>(offs, csrW, dinv, rowsum);

  // ---- Layer 1: F0 -> F1 (propagate after) ----
  mfma_gemm_split<128, false, true><<<dim3(MB, 1), 256, 0, stream>>>(
      nullptr, nullptr, x, W1h, W1l, be1, nullptr, A0b, nullptr, nullptr, N_NODES, F0, F1);
  agg128_rl<true, false><<<AGG_GRID, 256, 0, stream>>>(
      A0b, offs, csrS, csrW, dinv, B0f, nullptr, nullptr, stat4);
  bn_apply_f<F1, true, true, false, false><<<2048, 256, 0, stream>>>(
      B0f, stat4, g1, bb1, enc1, nullptr, nullptr, nullptr);

  // ---- Layer 2: F1 -> F2 (propagate after); GEMM reads enc1 fp32, splits in staging ----
  mfma_gemm_split<64, false, true><<<dim3(MB, 1), 256, 0, stream>>>(
      nullptr, nullptr, enc1, W2h, W2l, be2, nullptr, A1b, nullptr, nullptr, N_NODES, F1, F2);
  agg64_rl<true, false><<<AGG_GRID, 256, 0, stream>>>(
      A1b, offs, csrS, csrW, dinv, B0f, nullptr, nullptr, stat4 + 512);
  bn_apply_f<F2, false, true, true, false><<<2048, 256, 0, stream>>>(
      B0f, stat4 + 512, g2, bb2, enc2, C2b, nullptr, nullptr);

  // ---- Layer 3: F2 -> F1 (propagate FIRST) ----
  agg64_rl<false, true><<<AGG_GRID, 256, 0, stream>>>(
      C2b, offs, csrS, csrW, dinv, nullptr, G3hi, G3lo, nullptr);
  mfma_gemm_split<128, true, false><<<dim3(MB, 1), 256, 0, stream>>>(
      G3hi, G3lo, nullptr, W3h, W3l, bd1, rowsum, nullptr, B0f, stat4 + 1024, N_NODES, F2, F1);
  bn_apply_f<F1, true, false, true, false><<<2048, 256, 0, stream>>>(
      B0f, stat4 + 1024, g3, bb3, nullptr, D3b, nullptr, nullptr);

  // ---- Layer 4: F1 -> F0 (propagate FIRST) ----
  agg128_rl<false, true><<<AGG_GRID, 256, 0, stream>>>(
      D3b, offs, csrS, csrW, dinv, nullptr, G4hi, G4lo, nullptr);
  mfma_gemm_split<128, true, false><<<dim3(MB, 2), 256, 0, stream>>>(
      G4hi, G4lo, nullptr, W4h, W4l, bd2, rowsum, nullptr, B0f, stat4 + 1536, N_NODES, F1, F0);
  bn_apply_f<F0, false, true, false, false><<<2048, 256, 0, stream>>>(
      B0f, stat4 + 1536, g4, bb4, out, nullptr, nullptr, nullptr);
}